// Round 6
// baseline (159.300 us; speedup 1.0000x reference)
//
#include <hip/hip_runtime.h>

#define B_DIM 8192
#define H_DIM 1024
#define K_DIM 2048   // I + H
#define N_DIM 4096   // 4H
#define BH (B_DIM * H_DIM)
#define NT 32                // K-tiles (BK=64)
#define TSZ (256 * 64)       // elems per LDS tile buffer (32 KB)
#define HALFT (128 * 64)     // elems per half-tile

using frag_ab = __attribute__((ext_vector_type(8))) short;   // 8 bf16
using frag_cd = __attribute__((ext_vector_type(4))) float;

__device__ __forceinline__ unsigned short f2bf(float f) {
  union { float f; unsigned u; } x; x.f = f;
  return (unsigned short)((x.u + 0x7fffu + ((x.u >> 16) & 1u)) >> 16);
}

// ---- pack [xt | hx] -> bf16 A[8192][2048] ----
__global__ __launch_bounds__(256) void convert_A_kernel(
    const float* __restrict__ xt, const float* __restrict__ hx,
    unsigned short* __restrict__ Ab) {
  int tid = blockIdx.x * 256 + threadIdx.x;
  int flat = tid * 4;
  int m = flat >> 11;
  int k = flat & 2047;
  const float* src = (k < 1024) ? (xt + m * 1024 + k)
                                : (hx + m * 1024 + (k - 1024));
  float4 v = *reinterpret_cast<const float4*>(src);
  ushort4 o;
  o.x = f2bf(v.x); o.y = f2bf(v.y); o.z = f2bf(v.z); o.w = f2bf(v.w);
  *reinterpret_cast<ushort4*>(Ab + flat) = o;
}

// ---- pack gate-interleaved [W | R] -> bf16 B[4096][2048] ----
// output row n: tile=n>>8, c=n&255 -> gate=(c>>4)&3, h=tile*64+(c>>6)*16+(c&15)
__global__ __launch_bounds__(256) void convert_B_kernel(
    const float* __restrict__ w0, const float* __restrict__ w1,
    const float* __restrict__ w2, const float* __restrict__ w3,
    const float* __restrict__ r0, const float* __restrict__ r1,
    const float* __restrict__ r2, const float* __restrict__ r3,
    unsigned short* __restrict__ Bb) {
  int tid = blockIdx.x * 256 + threadIdx.x;
  int flat = tid * 4;
  int n = flat >> 11;
  int k = flat & 2047;
  int tile = n >> 8, c = n & 255;
  int gate = (c >> 4) & 3;
  int h = tile * 64 + ((c >> 6) << 4) + (c & 15);
  const float* wb = (gate == 0) ? w0 : (gate == 1) ? w1 : (gate == 2) ? w2 : w3;
  const float* rb = (gate == 0) ? r0 : (gate == 1) ? r1 : (gate == 2) ? r2 : r3;
  const float* src = (k < 1024) ? (wb + h * 1024 + k)
                                : (rb + h * 1024 + (k - 1024));
  float4 v = *reinterpret_cast<const float4*>(src);
  ushort4 o;
  o.x = f2bf(v.x); o.y = f2bf(v.y); o.z = f2bf(v.z); o.w = f2bf(v.w);
  *reinterpret_cast<ushort4*>(Bb + flat) = o;
}

__device__ __forceinline__ void gload_lds16(const void* g, void* l) {
  __builtin_amdgcn_global_load_lds(
      (const __attribute__((address_space(1))) unsigned int*)g,
      (__attribute__((address_space(3))) unsigned int*)l, 16, 0, 0);
}

__device__ __forceinline__ frag_ab ldsr(const unsigned short* buf, int byteoff) {
  return *reinterpret_cast<const frag_ab*>(
      reinterpret_cast<const char*>(buf) + byteoff);
}

__device__ __forceinline__ float fast_sigmoid(float x) {
  return 1.f / (1.f + __expf(-x));
}
__device__ __forceinline__ float fast_tanh(float x) {
  return 1.f - 2.f / (__expf(2.f * x) + 1.f);
}

#define CBAR asm volatile("" ::: "memory")
#define SBAR do { CBAR; __builtin_amdgcn_s_barrier(); CBAR; } while (0)
#define LGKM0 do { asm volatile("s_waitcnt lgkmcnt(0)" ::: "memory");          \
                   __builtin_amdgcn_sched_barrier(0); } while (0)
#define LGKM8 asm volatile("s_waitcnt lgkmcnt(8)" ::: "memory")

// m201-faithful phase: {same-phase ds_reads; stage; BAR; lgkmcnt(0); setprio;
// 16 MFMA; setprio; BAR}. Reads 12/4/8/0 per K-tile. Overlap arises from
// wave stagger through the lgkm wait (early waves MFMA while LDS queue drains).
// Stage ledger: P1/P2: A(t+1)h0/h1 -> Anx (A(t-1) dead since P3 of t-1).
//               P3/P4: B(t+2)h0/h1 -> Bc  (B(t) reads all complete by BAR2 of P2).
// vmcnt(4) at end of tile: drains A(t+1)+B(t+1), keeps B(t+2) (4 gloads) in
// flight. Never vmcnt(0) mid-loop.
#define TILE_BODY(Ac, Bc, Anx, tt, SA, SB, VM4, VM0)                           \
  {                                                                            \
    /* ---- P1: read A m0-3 (8) + B n0-1 (4); MFMA m0-3 x n0-1 ---- */         \
    _Pragma("unroll") for (int m = 0; m < 4; ++m)                              \
        _Pragma("unroll") for (int k = 0; k < 2; ++k)                          \
            Afr[m][k] = ldsr(Ac, (arow + m * 16) * 128 + (k ? c1 : c0));       \
    _Pragma("unroll") for (int n = 0; n < 2; ++n)                              \
        _Pragma("unroll") for (int k = 0; k < 2; ++k)                          \
            Bfr[n][k] = ldsr(Bc, (brow + n * 16) * 128 + (k ? c1 : c0));       \
    if (SA) stage(Ag + (size_t)((tt) + 1) * 64, (Anx));                        \
    LGKM8;                                                                     \
    SBAR;                                                                      \
    LGKM0;                                                                     \
    __builtin_amdgcn_s_setprio(1);                                             \
    _Pragma("unroll") for (int m = 0; m < 4; ++m)                              \
        _Pragma("unroll") for (int n = 0; n < 2; ++n)                          \
            _Pragma("unroll") for (int k = 0; k < 2; ++k)                      \
                acc[m][n] = __builtin_amdgcn_mfma_f32_16x16x32_bf16(           \
                    Afr[m][k], Bfr[n][k], acc[m][n], 0, 0, 0);                 \
    __builtin_amdgcn_s_setprio(0);                                             \
    SBAR;                                                                      \
    /* ---- P2: read B n2-3 (4); MFMA m0-3 x n2-3 ---- */                      \
    _Pragma("unroll") for (int n = 2; n < 4; ++n)                              \
        _Pragma("unroll") for (int k = 0; k < 2; ++k)                          \
            Bfr[n][k] = ldsr(Bc, (brow + n * 16) * 128 + (k ? c1 : c0));       \
    if (SA) stage(Ag + (size_t)((tt) + 1) * 64 + 128 * K_DIM, (Anx) + HALFT);  \
    SBAR;                                                                      \
    LGKM0;                                                                     \
    __builtin_amdgcn_s_setprio(1);                                             \
    _Pragma("unroll") for (int m = 0; m < 4; ++m)                              \
        _Pragma("unroll") for (int n = 2; n < 4; ++n)                          \
            _Pragma("unroll") for (int k = 0; k < 2; ++k)                      \
                acc[m][n] = __builtin_amdgcn_mfma_f32_16x16x32_bf16(           \
                    Afr[m][k], Bfr[n][k], acc[m][n], 0, 0, 0);                 \
    __builtin_amdgcn_s_setprio(0);                                             \
    SBAR;                                                                      \
    /* ---- P3: read A m4-7 (8); MFMA m4-7 x n0-1; stage B(t+2)h0 ---- */      \
    _Pragma("unroll") for (int m = 0; m < 4; ++m)                              \
        _Pragma("unroll") for (int k = 0; k < 2; ++k)                          \
            Afr[m][k] = ldsr(Ac, (arow + 64 + m * 16) * 128 + (k ? c1 : c0));  \
    if (SB) stage(Bg + (size_t)((tt) + 2) * 64, (Bc));                         \
    SBAR;                                                                      \
    LGKM0;                                                                     \
    __builtin_amdgcn_s_setprio(1);                                             \
    _Pragma("unroll") for (int m = 0; m < 4; ++m)                              \
        _Pragma("unroll") for (int n = 0; n < 2; ++n)                          \
            _Pragma("unroll") for (int k = 0; k < 2; ++k)                      \
                acc[4 + m][n] = __builtin_amdgcn_mfma_f32_16x16x32_bf16(       \
                    Afr[m][k], Bfr[n][k], acc[4 + m][n], 0, 0, 0);             \
    __builtin_amdgcn_s_setprio(0);                                             \
    SBAR;                                                                      \
    /* ---- P4: no reads; MFMA m4-7 x n2-3; stage B(t+2)h1; tile vmcnt ---- */ \
    if (SB) stage(Bg + (size_t)((tt) + 2) * 64 + 128 * K_DIM, (Bc) + HALFT);   \
    if (VM4) asm volatile("s_waitcnt vmcnt(4)" ::: "memory");                  \
    if (VM0) asm volatile("s_waitcnt vmcnt(0)" ::: "memory");                  \
    SBAR;                                                                      \
    __builtin_amdgcn_s_setprio(1);                                             \
    _Pragma("unroll") for (int m = 0; m < 4; ++m)                              \
        _Pragma("unroll") for (int n = 2; n < 4; ++n)                          \
            _Pragma("unroll") for (int k = 0; k < 2; ++k)                      \
                acc[4 + m][n] = __builtin_amdgcn_mfma_f32_16x16x32_bf16(       \
                    Afr[m][k], Bfr[n][k], acc[4 + m][n], 0, 0, 0);             \
    __builtin_amdgcn_s_setprio(0);                                             \
    SBAR;                                                                      \
  }

// ---- 256x256 tile GEMM, m201-port 4-phase K-loop, fused LSTM epilogue ----
__global__ __launch_bounds__(512, 2) void lstm_gemm_kernel(
    const unsigned short* __restrict__ Ab,   // [8192][2048] bf16
    const unsigned short* __restrict__ Bb,   // [4096][2048] bf16, gate-permuted
    const float* __restrict__ cx,
    const float* __restrict__ b_f, const float* __restrict__ b_i,
    const float* __restrict__ b_o, const float* __restrict__ b_g,
    float* __restrict__ out) {
  extern __shared__ unsigned short smem[];   // 128 KiB
  unsigned short* const As0 = smem;
  unsigned short* const As1 = smem + TSZ;
  unsigned short* const Bs0 = smem + 2 * TSZ;
  unsigned short* const Bs1 = smem + 3 * TSZ;

  const int bid = blockIdx.x;
  const int swz = (bid & 7) * 64 + (bid >> 3);    // 512 wgs % 8 == 0: bijective
  const int bm = swz >> 4;                        // 32 M-tiles
  const int bn = swz & 15;                        // 16 N-tiles

  const int tid = threadIdx.x;
  const int lane = tid & 63;
  const int wid = tid >> 6;
  const int wr = wid >> 2, wc = wid & 3;          // 2x4 waves, 128x64 each
  const int ln = lane & 15, kh = lane >> 4;

  const unsigned short* Ag = Ab + (size_t)(bm * 256) * K_DIM;
  const unsigned short* Bg = Bb + (size_t)(bn * 256) * K_DIM;

  // stage invariants: wave covers 16 rows of a 128-row half (2 gloads)
  const int srow = wid * 16 + (lane >> 3);
  const size_t gs0 = (size_t)srow * K_DIM + (((lane & 7) ^ (lane >> 3)) << 3);
  const size_t gs1 = gs0 + (size_t)8 * K_DIM;
  const int ld0 = wid * 2048 + lane * 16;         // LDS byte offsets (linear)
  const int ld1 = ld0 + 1024;
  auto stage = [&](const unsigned short* g, unsigned short* l) {
    gload_lds16(g + gs0, reinterpret_cast<char*>(l) + ld0);
    gload_lds16(g + gs1, reinterpret_cast<char*>(l) + ld1);
  };

  // read invariants (byte offsets; XOR swizzle with loop-invariant key)
  const int inv = (ln & 7) << 4;
  const int c0 = (kh * 16) ^ inv;                 // kk0 column
  const int c1 = (64 + kh * 16) ^ inv;            // kk1 column
  const int arow = wr * 128 + ln;
  const int brow = wc * 64 + ln;

  frag_cd acc[8][4] = {};
  frag_ab Afr[4][2], Bfr[4][2];

  // ---- prologue: A(0), B(0), B(1) (12 gloads); keep B(1) in flight ----
  stage(Ag, As0);
  stage(Ag + 128 * K_DIM, As0 + HALFT);
  stage(Bg, Bs0);
  stage(Bg + 128 * K_DIM, Bs0 + HALFT);
  stage(Bg + 64, Bs1);
  stage(Bg + 64 + 128 * K_DIM, Bs1 + HALFT);
  asm volatile("s_waitcnt vmcnt(4)" ::: "memory");   // A(0),B(0) landed
  SBAR;

  // ---- main loop: 2 K-tiles per iter, static buffers ----
  for (int u = 0; u < 15; ++u) {
    const int e = 2 * u;
    TILE_BODY(As0, Bs0, As1, e, 1, 1, 1, 0);
    TILE_BODY(As1, Bs1, As0, e + 1, 1, 1, 1, 0);
  }
  // t=30: stage A(31); no B(32); drain all outstanding
  TILE_BODY(As0, Bs0, As1, 30, 1, 0, 0, 1);
  // t=31: pure compute
  TILE_BODY(As1, Bs1, As0, 31, 0, 0, 0, 0);

  // ---- fused LSTM epilogue: n-frag == gate, h = bn*64 + wc*16 + ln ----
  const int hcol = bn * 64 + wc * 16 + ln;
  const float bfv = b_f[hcol], biv = b_i[hcol], bov = b_o[hcol], bgv = b_g[hcol];
  const int row_base = bm * 256 + wr * 128 + kh * 4;
#pragma unroll
  for (int mi = 0; mi < 8; ++mi) {
#pragma unroll
    for (int j = 0; j < 4; ++j) {
      const int row = row_base + mi * 16 + j;
      float fp = acc[mi][0][j] + bfv;
      float ip = acc[mi][1][j] + biv;
      float op = acc[mi][2][j] + bov;
      float gp = acc[mi][3][j] + bgv;
      float ft = fast_sigmoid(fp);
      float it = fast_sigmoid(ip);
      float ot = fast_sigmoid(op);
      float gt = fast_tanh(gp);
      float cold = cx[(size_t)row * H_DIM + hcol];
      float ct = ft * cold + it * gt;
      float ht = ot * fast_tanh(ct);
      out[(size_t)row * H_DIM + hcol] = ht;
      out[BH + (size_t)row * H_DIM + hcol] = ct;
    }
  }
}

extern "C" void kernel_launch(void* const* d_in, const int* in_sizes, int n_in,
                              void* d_out, int out_size, void* d_ws, size_t ws_size,
                              hipStream_t stream) {
  const float* xt   = (const float*)d_in[0];
  const float* cxp  = (const float*)d_in[1];
  const float* hx   = (const float*)d_in[2];
  const float* w_fg = (const float*)d_in[3];
  const float* w_ig = (const float*)d_in[4];
  const float* w_og = (const float*)d_in[5];
  const float* w_ci = (const float*)d_in[6];
  const float* r_fg = (const float*)d_in[7];
  const float* r_ig = (const float*)d_in[8];
  const float* r_og = (const float*)d_in[9];
  const float* r_ci = (const float*)d_in[10];
  const float* b_fg = (const float*)d_in[11];
  const float* b_ig = (const float*)d_in[12];
  const float* b_og = (const float*)d_in[13];
  const float* b_ci = (const float*)d_in[14];

  unsigned short* Abf = (unsigned short*)d_ws;                // 33.5 MB
  unsigned short* Bbf = Abf + (size_t)B_DIM * K_DIM;          // 16.8 MB
  float* out = (float*)d_out;

  convert_A_kernel<<<dim3(B_DIM * K_DIM / 4 / 256), dim3(256), 0, stream>>>(
      xt, hx, Abf);
  convert_B_kernel<<<dim3(N_DIM * K_DIM / 4 / 256), dim3(256), 0, stream>>>(
      w_fg, w_ig, w_og, w_ci, r_fg, r_ig, r_og, r_ci, Bbf);
  lstm_gemm_kernel<<<dim3((B_DIM / 256) * (N_DIM / 256)), dim3(512),
                     131072, stream>>>(
      Abf, Bbf, cxp, b_fg, b_ig, b_og, b_ci, out);
}

// Round 7
// 157.473 us; speedup vs baseline: 1.0116x; 1.0116x over previous
//
#include <hip/hip_runtime.h>

#define B_DIM 8192
#define H_DIM 1024
#define K_DIM 2048   // I + H
#define N_DIM 4096   // 4H
#define BH (B_DIM * H_DIM)
#define NT 32                // K-tiles (BK=64)
#define TSZ (256 * 64)       // elems per LDS tile buffer (32 KB)
#define HALFT (128 * 64)     // elems per half-tile

using frag_ab = __attribute__((ext_vector_type(8))) short;   // 8 bf16
using frag_cd = __attribute__((ext_vector_type(4))) float;

__device__ __forceinline__ unsigned short f2bf(float f) {
  union { float f; unsigned u; } x; x.f = f;
  return (unsigned short)((x.u + 0x7fffu + ((x.u >> 16) & 1u)) >> 16);
}

// ---- pack [xt | hx] -> bf16 A[8192][2048] ----
__global__ __launch_bounds__(256) void convert_A_kernel(
    const float* __restrict__ xt, const float* __restrict__ hx,
    unsigned short* __restrict__ Ab) {
  int tid = blockIdx.x * 256 + threadIdx.x;
  int flat = tid * 4;
  int m = flat >> 11;
  int k = flat & 2047;
  const float* src = (k < 1024) ? (xt + m * 1024 + k)
                                : (hx + m * 1024 + (k - 1024));
  float4 v = *reinterpret_cast<const float4*>(src);
  ushort4 o;
  o.x = f2bf(v.x); o.y = f2bf(v.y); o.z = f2bf(v.z); o.w = f2bf(v.w);
  *reinterpret_cast<ushort4*>(Ab + flat) = o;
}

// ---- pack gate-interleaved [W | R] -> bf16 B[4096][2048] ----
// output row n: tile=n>>8, c=n&255 -> gate=(c>>4)&3, h=tile*64+(c>>6)*16+(c&15)
__global__ __launch_bounds__(256) void convert_B_kernel(
    const float* __restrict__ w0, const float* __restrict__ w1,
    const float* __restrict__ w2, const float* __restrict__ w3,
    const float* __restrict__ r0, const float* __restrict__ r1,
    const float* __restrict__ r2, const float* __restrict__ r3,
    unsigned short* __restrict__ Bb) {
  int tid = blockIdx.x * 256 + threadIdx.x;
  int flat = tid * 4;
  int n = flat >> 11;
  int k = flat & 2047;
  int tile = n >> 8, c = n & 255;
  int gate = (c >> 4) & 3;
  int h = tile * 64 + ((c >> 6) << 4) + (c & 15);
  const float* wb = (gate == 0) ? w0 : (gate == 1) ? w1 : (gate == 2) ? w2 : w3;
  const float* rb = (gate == 0) ? r0 : (gate == 1) ? r1 : (gate == 2) ? r2 : r3;
  const float* src = (k < 1024) ? (wb + h * 1024 + k)
                                : (rb + h * 1024 + (k - 1024));
  float4 v = *reinterpret_cast<const float4*>(src);
  ushort4 o;
  o.x = f2bf(v.x); o.y = f2bf(v.y); o.z = f2bf(v.z); o.w = f2bf(v.w);
  *reinterpret_cast<ushort4*>(Bb + flat) = o;
}

__device__ __forceinline__ void gload_lds16(const void* g, void* l) {
  __builtin_amdgcn_global_load_lds(
      (const __attribute__((address_space(1))) unsigned int*)g,
      (__attribute__((address_space(3))) unsigned int*)l, 16, 0, 0);
}

__device__ __forceinline__ frag_ab ldsr(const unsigned short* buf, int byteoff) {
  return *reinterpret_cast<const frag_ab*>(
      reinterpret_cast<const char*>(buf) + byteoff);
}

__device__ __forceinline__ float fast_sigmoid(float x) {
  return 1.f / (1.f + __expf(-x));
}
__device__ __forceinline__ float fast_tanh(float x) {
  return 1.f - 2.f / (__expf(2.f * x) + 1.f);
}

#define CBAR asm volatile("" ::: "memory")
#define SBAR do { CBAR; __builtin_amdgcn_s_barrier(); CBAR; } while (0)
#define SCHED0 __builtin_amdgcn_sched_barrier(0)

// Decoupled phase: {ds_reads; stage; setprio; MFMA (compiler per-use lgkm);
// setprio; sched_barrier(0); s_barrier}. NO barrier/lgkm0 between reads and
// MFMA: each wave starts its MFMAs as soon as ITS OWN reads land -> waves
// stagger, LDS pipe serves late waves while early waves' matrix pipes run.
// Barrier after MFMA is the stage-WAR publication point (ledger: every stage
// victim's last reader is >=2 barriers back; reads complete pre-barrier since
// their consuming MFMAs are pinned above the barrier by sched_barrier(0)).
// Stage ledger: Q1: B(t+1)h1->Bnx+HALFT | Q2: A(t+1)h0->Anx |
//               Q3: A(t+1)h1->Anx+HALFT | Q4: B(t+2)h0->Bc.
// vmcnt(2) end of tile (10 outstanding -> drain 8: A(t+1),B(t+1); keep
// B(t+2)h0 in flight). Never vmcnt(0) mid-loop.
#define TILE_BODY(Ac, Bc, Anx, Bnx, tt, S1, S2, S3, S4, VM2, VM0)             \
  {                                                                            \
    /* ---- Q1: reads kk0 (A m0-3, B n0-3); stage B(t+1)h1; MFMA kk0 ---- */   \
    _Pragma("unroll") for (int m = 0; m < 4; ++m)                              \
        Af0[m] = ldsr(Ac, (arow + m * 16) * 128 + c0);                         \
    _Pragma("unroll") for (int n = 0; n < 4; ++n)                              \
        Bf0[n] = ldsr(Bc, (brow + n * 16) * 128 + c0);                         \
    if (S1) stage(Bg + 128 * K_DIM + (size_t)((tt) + 1) * 64, (Bnx) + HALFT);  \
    __builtin_amdgcn_s_setprio(1);                                             \
    _Pragma("unroll") for (int m = 0; m < 4; ++m)                              \
        _Pragma("unroll") for (int n = 0; n < 4; ++n)                          \
            acc[m][n] = __builtin_amdgcn_mfma_f32_16x16x32_bf16(               \
                Af0[m], Bf0[n], acc[m][n], 0, 0, 0);                           \
    __builtin_amdgcn_s_setprio(0);                                             \
    SCHED0;                                                                    \
    SBAR;                                                                      \
    /* ---- Q2: reads kk1 (A m0-3, B n0-3); stage A(t+1)h0; MFMA kk1 ---- */   \
    _Pragma("unroll") for (int m = 0; m < 4; ++m)                              \
        Af1[m] = ldsr(Ac, (arow + m * 16) * 128 + c1);                         \
    _Pragma("unroll") for (int n = 0; n < 4; ++n)                              \
        Bf1[n] = ldsr(Bc, (brow + n * 16) * 128 + c1);                         \
    if (S2) stage(Ag + (size_t)((tt) + 1) * 64, (Anx));                        \
    __builtin_amdgcn_s_setprio(1);                                             \
    _Pragma("unroll") for (int m = 0; m < 4; ++m)                              \
        _Pragma("unroll") for (int n = 0; n < 4; ++n)                          \
            acc[m][n] = __builtin_amdgcn_mfma_f32_16x16x32_bf16(               \
                Af1[m], Bf1[n], acc[m][n], 0, 0, 0);                           \
    __builtin_amdgcn_s_setprio(0);                                             \
    SCHED0;                                                                    \
    SBAR;                                                                      \
    /* ---- Q3: reads A m4-7 kk0; stage A(t+1)h1; MFMA (Bf0 held) ---- */      \
    _Pragma("unroll") for (int m = 0; m < 4; ++m)                              \
        Af0[m] = ldsr(Ac, (arow + 64 + m * 16) * 128 + c0);                    \
    if (S3) stage(Ag + (size_t)((tt) + 1) * 64 + 128 * K_DIM, (Anx) + HALFT);  \
    __builtin_amdgcn_s_setprio(1);                                             \
    _Pragma("unroll") for (int m = 0; m < 4; ++m)                              \
        _Pragma("unroll") for (int n = 0; n < 4; ++n)                          \
            acc[4 + m][n] = __builtin_amdgcn_mfma_f32_16x16x32_bf16(           \
                Af0[m], Bf0[n], acc[4 + m][n], 0, 0, 0);                       \
    __builtin_amdgcn_s_setprio(0);                                             \
    SCHED0;                                                                    \
    SBAR;                                                                      \
    /* ---- Q4: reads A m4-7 kk1; stage B(t+2)h0->Bc; MFMA; tile vmcnt ---- */ \
    _Pragma("unroll") for (int m = 0; m < 4; ++m)                              \
        Af1[m] = ldsr(Ac, (arow + 64 + m * 16) * 128 + c1);                    \
    if (S4) stage(Bg + (size_t)((tt) + 2) * 64, (Bc));                         \
    __builtin_amdgcn_s_setprio(1);                                             \
    _Pragma("unroll") for (int m = 0; m < 4; ++m)                              \
        _Pragma("unroll") for (int n = 0; n < 4; ++n)                          \
            acc[4 + m][n] = __builtin_amdgcn_mfma_f32_16x16x32_bf16(           \
                Af1[m], Bf1[n], acc[4 + m][n], 0, 0, 0);                       \
    __builtin_amdgcn_s_setprio(0);                                             \
    if (VM2) asm volatile("s_waitcnt vmcnt(2)" ::: "memory");                  \
    if (VM0) asm volatile("s_waitcnt vmcnt(0)" ::: "memory");                  \
    SCHED0;                                                                    \
    SBAR;                                                                      \
  }

// ---- 256x256 tile GEMM, decoupled-wait phases, fused LSTM epilogue ----
__global__ __launch_bounds__(512, 2) void lstm_gemm_kernel(
    const unsigned short* __restrict__ Ab,   // [8192][2048] bf16
    const unsigned short* __restrict__ Bb,   // [4096][2048] bf16, gate-permuted
    const float* __restrict__ cx,
    const float* __restrict__ b_f, const float* __restrict__ b_i,
    const float* __restrict__ b_o, const float* __restrict__ b_g,
    float* __restrict__ out) {
  extern __shared__ unsigned short smem[];   // 128 KiB
  unsigned short* const As0 = smem;
  unsigned short* const As1 = smem + TSZ;
  unsigned short* const Bs0 = smem + 2 * TSZ;
  unsigned short* const Bs1 = smem + 3 * TSZ;

  const int bid = blockIdx.x;
  const int swz = (bid & 7) * 64 + (bid >> 3);    // 512 wgs % 8 == 0: bijective
  const int bm = swz >> 4;                        // 32 M-tiles
  const int bn = swz & 15;                        // 16 N-tiles

  const int tid = threadIdx.x;
  const int lane = tid & 63;
  const int wid = tid >> 6;
  const int wr = wid >> 2, wc = wid & 3;          // 2x4 waves, 128x64 each
  const int ln = lane & 15, kh = lane >> 4;

  const unsigned short* Ag = Ab + (size_t)(bm * 256) * K_DIM;
  const unsigned short* Bg = Bb + (size_t)(bn * 256) * K_DIM;

  // stage invariants: wave covers 16 rows of a 128-row half (2 gloads)
  const size_t gs0 = (size_t)(wid * 16 + (lane >> 3)) * K_DIM +
                     (((lane & 7) ^ (lane >> 3)) << 3);
  const size_t gs1 = gs0 + (size_t)8 * K_DIM;
  const int ld0 = wid * 2048 + lane * 16;         // LDS byte offsets (linear)
  const int ld1 = ld0 + 1024;
  auto stage = [&](const unsigned short* g, unsigned short* l) {
    gload_lds16(g + gs0, reinterpret_cast<char*>(l) + ld0);
    gload_lds16(g + gs1, reinterpret_cast<char*>(l) + ld1);
  };

  // read invariants (byte offsets; XOR swizzle with loop-invariant key)
  const int inv = (ln & 7) << 4;
  const int c0 = (kh * 16) ^ inv;                 // kk0 column
  const int c1 = (64 + kh * 16) ^ inv;            // kk1 column
  const int arow = wr * 128 + ln;
  const int brow = wc * 64 + ln;

  frag_cd acc[8][4] = {};
  frag_ab Af0[4], Af1[4], Bf0[4], Bf1[4];

  // ---- prologue: A(0), B(0) full + B(1)h0 (10 gloads); keep B(1)h0 flying --
  stage(Ag, As0);
  stage(Ag + 128 * K_DIM, As0 + HALFT);
  stage(Bg, Bs0);
  stage(Bg + 128 * K_DIM, Bs0 + HALFT);
  stage(Bg + 64, Bs1);
  asm volatile("s_waitcnt vmcnt(2)" ::: "memory");   // A(0),B(0) landed
  SBAR;

  // ---- main loop: 2 K-tiles per iter, static buffers ----
  for (int u = 0; u < 15; ++u) {
    const int e = 2 * u;
    TILE_BODY(As0, Bs0, As1, Bs1, e, 1, 1, 1, 1, 1, 0);
    TILE_BODY(As1, Bs1, As0, Bs0, e + 1, 1, 1, 1, 1, 1, 0);
  }
  // t=30: stage B(31)h1 + A(31); skip B(32); drain all
  TILE_BODY(As0, Bs0, As1, Bs1, 30, 1, 1, 1, 0, 0, 1);
  // t=31: pure compute
  TILE_BODY(As1, Bs1, As0, Bs0, 31, 0, 0, 0, 0, 0, 0);

  // ---- fused LSTM epilogue: n-frag == gate, h = bn*64 + wc*16 + ln ----
  const int hcol = bn * 64 + wc * 16 + ln;
  const float bfv = b_f[hcol], biv = b_i[hcol], bov = b_o[hcol], bgv = b_g[hcol];
  const int row_base = bm * 256 + wr * 128 + kh * 4;
#pragma unroll
  for (int mi = 0; mi < 8; ++mi) {
#pragma unroll
    for (int j = 0; j < 4; ++j) {
      const int row = row_base + mi * 16 + j;
      float fp = acc[mi][0][j] + bfv;
      float ip = acc[mi][1][j] + biv;
      float op = acc[mi][2][j] + bov;
      float gp = acc[mi][3][j] + bgv;
      float ft = fast_sigmoid(fp);
      float it = fast_sigmoid(ip);
      float ot = fast_sigmoid(op);
      float gt = fast_tanh(gp);
      float cold = cx[(size_t)row * H_DIM + hcol];
      float ct = ft * cold + it * gt;
      float ht = ot * fast_tanh(ct);
      out[(size_t)row * H_DIM + hcol] = ht;
      out[BH + (size_t)row * H_DIM + hcol] = ct;
    }
  }
}

extern "C" void kernel_launch(void* const* d_in, const int* in_sizes, int n_in,
                              void* d_out, int out_size, void* d_ws, size_t ws_size,
                              hipStream_t stream) {
  const float* xt   = (const float*)d_in[0];
  const float* cxp  = (const float*)d_in[1];
  const float* hx   = (const float*)d_in[2];
  const float* w_fg = (const float*)d_in[3];
  const float* w_ig = (const float*)d_in[4];
  const float* w_og = (const float*)d_in[5];
  const float* w_ci = (const float*)d_in[6];
  const float* r_fg = (const float*)d_in[7];
  const float* r_ig = (const float*)d_in[8];
  const float* r_og = (const float*)d_in[9];
  const float* r_ci = (const float*)d_in[10];
  const float* b_fg = (const float*)d_in[11];
  const float* b_ig = (const float*)d_in[12];
  const float* b_og = (const float*)d_in[13];
  const float* b_ci = (const float*)d_in[14];

  unsigned short* Abf = (unsigned short*)d_ws;                // 33.5 MB
  unsigned short* Bbf = Abf + (size_t)B_DIM * K_DIM;          // 16.8 MB
  float* out = (float*)d_out;

  convert_A_kernel<<<dim3(B_DIM * K_DIM / 4 / 256), dim3(256), 0, stream>>>(
      xt, hx, Abf);
  convert_B_kernel<<<dim3(N_DIM * K_DIM / 4 / 256), dim3(256), 0, stream>>>(
      w_fg, w_ig, w_og, w_ci, r_fg, r_ig, r_og, r_ci, Bbf);
  lstm_gemm_kernel<<<dim3((B_DIM / 256) * (N_DIM / 256)), dim3(512),
                     131072, stream>>>(
      Abf, Bbf, cxp, b_fg, b_ig, b_og, b_ci, out);
}